// Round 5
// baseline (5574.744 us; speedup 1.0000x reference)
//
#include <hip/hip_runtime.h>
#include <stdint.h>

// ContTimeLSTM: B=128, L=512, I=256, D=512.
// Inputs f32 (x, dt, bos, W, bias) + int32 seq_lens. Output f32.
// bf16 internal for the MFMA projection (tolerance floor 8*eps_bf16 = 0.03125;
// measured absmax 0.0078 with this scheme in round 4).
constexpr int B_   = 128;
constexpr int L_   = 512;
constexpr int I_   = 256;
constexpr int D_   = 512;
constexpr int KTOT = I_ + D_;     // 768
constexpr int ND7  = 7 * D_;      // 3584
constexpr int RW   = 16;          // rows per workgroup
constexpr int MW   = 16;          // m (state dim) per workgroup
constexpr int RG   = B_ / RW;     // 8 row groups (rg = bid & 7 -> XCD-local)
constexpr int MG   = D_ / MW;     // 32 m groups = blocks per row-group barrier
constexpr int NWG  = RG * MG;     // 256 workgroups (1 per CU)
constexpr int NTHR = 256;         // 4 waves
constexpr int PS   = 122;         // padded LDS row stride (floats)
constexpr int FSTR = 16;          // flag stride in ints (64 B)

typedef short  bfrag8 __attribute__((ext_vector_type(8)));  // 8 bf16 (4 VGPRs)
typedef float  f32x4  __attribute__((ext_vector_type(4)));

__device__ __forceinline__ unsigned short f2bf(float f) {
    union { float f; uint32_t i; } v; v.f = f;
    uint32_t x = v.i;
    return (unsigned short)((x + 0x7fffu + ((x >> 16) & 1u)) >> 16);  // RNE
}
__device__ __forceinline__ bfrag8 pack8(float4 a, float4 b) {
    bfrag8 r;
    r[0] = (short)f2bf(a.x); r[1] = (short)f2bf(a.y);
    r[2] = (short)f2bf(a.z); r[3] = (short)f2bf(a.w);
    r[4] = (short)f2bf(b.x); r[5] = (short)f2bf(b.y);
    r[6] = (short)f2bf(b.z); r[7] = (short)f2bf(b.w);
    return r;
}
__device__ __forceinline__ float sigm(float x) { return 1.0f / (1.0f + __expf(-x)); }
__device__ __forceinline__ float tanh_f(float x) {
    float xc = fminf(fmaxf(x, -15.f), 15.f);
    float e  = __expf(2.f * xc);
    return (e - 1.f) / (e + 1.f);
}
__device__ __forceinline__ float softplus_f(float x) {
    return (x > 15.f) ? x : log1pf(__expf(x));
}

// Prologue: proj0[j] = dot(W[j, 0:I], bos) + bias[j]  (BOS step, zero state)
__global__ void bos_proj_kernel(const float* __restrict__ W,
                                const float* __restrict__ bos,
                                const float* __restrict__ bias,
                                float* __restrict__ proj0) {
    int j = blockIdx.x * blockDim.x + threadIdx.x;
    if (j >= ND7) return;
    const float* wr = W + (size_t)j * KTOT;
    float s = 0.f;
#pragma unroll 8
    for (int k = 0; k < I_; ++k) s += wr[k] * bos[k];
    proj0[j] = s + bias[j];
}

// Persistent recurrence kernel.
// WG (rg,mg): rows b0..b0+15, state dims m0..m0+15, proj cols {g*512+m0+0..15}.
// Weights pinned in VGPRs (bf16): wave w holds K-steps s = w+4i (i=0..5), 7 N-tiles.
// Sync: per-row-group flag-array barrier; flag[mg] = t+1 published with release,
// wave 0 polls all 32 flags lane-parallel; monotone -> no reset, no RMW chain.
__global__ void __launch_bounds__(NTHR, 1)
ctlstm_kernel(const float* __restrict__ X,     // (B,L,I) f32
              const float* __restrict__ DT,    // (B,L)   f32
              const int*   __restrict__ SEQ,   // (B,)    int32
              const float* __restrict__ W,     // (7D, K) f32
              const float* __restrict__ BIAS,  // (7D,)   f32
              const float* __restrict__ PROJ0, // (7D,)   f32
              unsigned short* __restrict__ HBUF, // (2,B,D) bf16 ping-pong
              int*   __restrict__ FLAGS,       // RG*MG flags, 64 B apart
              float* __restrict__ OUT)         // f32: outputs (B,L,D) | final (B,4D)
{
    __shared__ float lds[4 * RW * PS];

    const int tid  = threadIdx.x;
    const int wid  = tid >> 6;      // wave 0..3
    const int lane = tid & 63;
    const int bid  = blockIdx.x;
    const int rg   = bid & 7;       // row group (XCD-local under round-robin)
    const int mg   = bid >> 3;      // m group
    const int b0   = rg * RW;
    const int m0   = mg * MW;

    // elementwise mapping: thread <-> (row, mi)
    const int erow = tid >> 4;
    const int emi  = tid & 15;
    const int eb   = b0 + erow;
    const int em   = m0 + emi;
    const int esl  = SEQ[eb];

    // MFMA lane mapping
    const int lrow = lane & 15;     // A row (batch) / B,C col
    const int lq   = lane >> 4;     // quad -> k-octet / C row block
    const int lb   = b0 + lrow;
    const int lsl  = SEQ[lb];

    int* myflag   = FLAGS + (rg * MG + mg) * FSTR;
    const int* pollflag = FLAGS + (rg * MG + (lane & 31)) * FSTR;

    // ---- pin B fragments (weights, f32 -> bf16 RNE): Bf[i][g], K-step s=wid+4i
    bfrag8 Bf[6][7];
#pragma unroll
    for (int i = 0; i < 6; ++i) {
        const int s = wid + 4 * i;
        const int k = s * 32 + lq * 8;
#pragma unroll
        for (int g = 0; g < 7; ++g) {
            const int j = g * D_ + m0 + lrow;       // proj column
            const float4* wp = (const float4*)(W + (size_t)j * KTOT + k);
            Bf[i][g] = pack8(wp[0], wp[1]);
        }
    }

    // bias per elementwise thread (f32)
    float bg[7];
#pragma unroll
    for (int g = 0; g < 7; ++g) bg[g] = BIAS[g * D_ + em];

    // ---- initial state from BOS projection (same for every batch row)
    float p0[7];
#pragma unroll
    for (int g = 0; g < 7; ++g) p0[g] = PROJ0[g * D_ + em];
    float z0  = tanh_f(p0[5]);
    float so  = sigm(p0[4]);          // o
    float scs = sigm(p0[0]) * z0;     // cs = i*z  (c=0)
    float sce = sigm(p0[2]) * z0;     // ce = ie*z (ce=0)
    float sd  = softplus_f(p0[6]);    // d

    const size_t OUTF = (size_t)B_ * L_ * D_;   // final-state offset (f32 elems)

    for (int t = 0; t < L_; ++t) {
        // ---- phase 1: decay + h (uses previous state; local)
        float dtt = (t < esl) ? DT[(size_t)eb * L_ + t] : 0.f;
        float c   = sce + (scs - sce) * __expf(-sd * dtt);
        float h   = so * tanh_f(c);
        HBUF[(size_t)((t & 1) * B_ + eb) * D_ + em] = f2bf(h);  // L2-cached

        __syncthreads();   // drains every wave's HBUF stores (vmcnt0 + barrier)

        // ---- publish: release-store my flag (wbl2 flushes only h slices; OUT
        //      is non-temporal and never dirties L2)
        if (tid == 0)
            __hip_atomic_store(myflag, t + 1, __ATOMIC_RELEASE,
                               __HIP_MEMORY_SCOPE_AGENT);

        // ---- off-critical-path: f32 output store (non-temporal)
        __builtin_nontemporal_store(h, &OUT[((size_t)eb * L_ + t) * D_ + em]);

        // ---- x fragments (s = wid, wid+4), f32 -> bf16; h-independent
        bfrag8 ax[2];
#pragma unroll
        for (int i = 0; i < 2; ++i) {
            const int s = wid + 4 * i;
            const int k = s * 32 + lq * 8;
            float4 xa = {0.f, 0.f, 0.f, 0.f}, xb = {0.f, 0.f, 0.f, 0.f};
            if (t < lsl) {
                const float4* xp = (const float4*)(X + ((size_t)lb * L_ + t) * I_ + k);
                xa = xp[0]; xb = xp[1];
            }
            ax[i] = pack8(xa, xb);
        }

        // ---- x-part MFMAs while the barrier settles
        f32x4 acc[7];
#pragma unroll
        for (int g = 0; g < 7; ++g) acc[g] = (f32x4){0.f, 0.f, 0.f, 0.f};
#pragma unroll
        for (int i = 0; i < 2; ++i)
#pragma unroll
            for (int g = 0; g < 7; ++g)
                acc[g] = __builtin_amdgcn_mfma_f32_16x16x32_bf16(ax[i], Bf[i][g], acc[g], 0, 0, 0);

        // ---- wait: wave 0 polls all 32 flags lane-parallel
        if (wid == 0) {
            while (true) {
                int v = __hip_atomic_load(pollflag, __ATOMIC_RELAXED,
                                          __HIP_MEMORY_SCOPE_AGENT);
                if (__all(v >= t + 1)) break;
                __builtin_amdgcn_s_sleep(1);
            }
            __builtin_amdgcn_fence(__ATOMIC_ACQUIRE, "agent");
        }
        __syncthreads();

        // ---- load h fragments (s = 8..23 -> k within D), bf16
        bfrag8 ah[4];
#pragma unroll
        for (int i = 2; i < 6; ++i) {
            const int s = wid + 4 * i;
            const int k = (s - 8) * 32 + lq * 8;
            ah[i - 2] = *(const bfrag8*)(HBUF + (size_t)((t & 1) * B_ + lb) * D_ + k);
        }

        // ---- h-part MFMAs
#pragma unroll
        for (int i = 2; i < 6; ++i)
#pragma unroll
            for (int g = 0; g < 7; ++g)
                acc[g] = __builtin_amdgcn_mfma_f32_16x16x32_bf16(ah[i - 2], Bf[i][g], acc[g], 0, 0, 0);

        // ---- cross-wave K-reduction via LDS
        // C/D layout: col = lane&15, row = (lane>>4)*4 + reg  (m89/m91)
#pragma unroll
        for (int g = 0; g < 7; ++g)
#pragma unroll
            for (int r = 0; r < 4; ++r)
                lds[(wid * RW + lq * 4 + r) * PS + g * 16 + lrow] = acc[g][r];

        __syncthreads();

        // ---- phase 4: gates + state update (local)
        float p[7];
#pragma unroll
        for (int g = 0; g < 7; ++g) {
            float s = bg[g];
#pragma unroll
            for (int w2 = 0; w2 < 4; ++w2)
                s += lds[(w2 * RW + erow) * PS + g * 16 + emi];
            p[g] = s;
        }
        float ig  = sigm(p[0]);
        float fg  = sigm(p[1]);
        float ieg = sigm(p[2]);
        float feg = sigm(p[3]);
        float on  = sigm(p[4]);
        float z   = tanh_f(p[5]);
        float dn  = softplus_f(p[6]);
        float csn = fg * c + ig * z;
        float cen = feg * sce + ieg * z;
        so = on; scs = csn; sce = cen; sd = dn;

        if (t == esl - 1) {   // capture final state (post-update) at seq_len-1
            size_t fo = OUTF + (size_t)eb * (4 * D_) + em;
            __builtin_nontemporal_store(on,  &OUT[fo]);
            __builtin_nontemporal_store(csn, &OUT[fo + D_]);
            __builtin_nontemporal_store(cen, &OUT[fo + 2 * D_]);
            __builtin_nontemporal_store(dn,  &OUT[fo + 3 * D_]);
        }
        // LDS WAR across steps guarded by the pre-flag + post-spin barriers
    }
}

extern "C" void kernel_launch(void* const* d_in, const int* in_sizes, int n_in,
                              void* d_out, int out_size, void* d_ws, size_t ws_size,
                              hipStream_t stream) {
    const float* X   = (const float*)d_in[0];
    const float* DT  = (const float*)d_in[1];
    const int*   SEQ = (const int*)d_in[2];
    const float* BOS = (const float*)d_in[3];
    const float* W   = (const float*)d_in[4];
    const float* BI  = (const float*)d_in[5];
    float*       OUT = (float*)d_out;

    float*          proj0 = (float*)d_ws;                              // 14336 B
    int*            flags = (int*)((char*)d_ws + 16384);               // 256 x 64 B
    unsigned short* hbuf  = (unsigned short*)((char*)d_ws + 49152);    // 2*B*D bf16 = 256 KB

    // flags must start at zero (d_ws is poisoned 0xAA each call)
    hipMemsetAsync((char*)d_ws + 16384, 0, 16384, stream);

    bos_proj_kernel<<<(ND7 + 255) / 256, 256, 0, stream>>>(W, BOS, BI, proj0);

    ctlstm_kernel<<<dim3(NWG), dim3(NTHR), 0, stream>>>(
        X, DT, SEQ, W, BI, proj0, hbuf, flags, OUT);
}

// Round 6
// 1988.082 us; speedup vs baseline: 2.8041x; 2.8041x over previous
//
#include <hip/hip_runtime.h>
#include <stdint.h>

// ContTimeLSTM: B=128, L=512, I=256, D=512.
// Inputs f32 (x, dt, bos, W, bias) + int32 seq_lens. Output f32.
// bf16 internal for the MFMA projection (tolerance floor 8*eps_bf16 = 0.03125;
// measured absmax 0.0078 rounds 4/5).
//
// Round 6: h exchanged through LLC-coherent (sc0 sc1) write-through stores and
// L2-bypassing loads -> no buffer_wbl2 / L2-invalidate on the per-step barrier.
constexpr int B_   = 128;
constexpr int L_   = 512;
constexpr int I_   = 256;
constexpr int D_   = 512;
constexpr int KTOT = I_ + D_;     // 768
constexpr int ND7  = 7 * D_;      // 3584
constexpr int RW   = 16;          // rows per workgroup
constexpr int MW   = 16;          // m (state dim) per workgroup
constexpr int RG   = B_ / RW;     // 8 row groups (rg = bid & 7 -> XCD-local)
constexpr int MG   = D_ / MW;     // 32 m groups = blocks per row-group barrier
constexpr int NWG  = RG * MG;     // 256 workgroups (1 per CU)
constexpr int NTHR = 256;         // 4 waves
constexpr int PS   = 122;         // padded LDS row stride (floats)
constexpr int FSTR = 16;          // flag stride in ints (64 B)

typedef short  bfrag8 __attribute__((ext_vector_type(8)));  // 8 bf16 (4 VGPRs)
typedef float  f32x4  __attribute__((ext_vector_type(4)));

__device__ __forceinline__ unsigned short f2bf(float f) {
    union { float f; uint32_t i; } v; v.f = f;
    uint32_t x = v.i;
    return (unsigned short)((x + 0x7fffu + ((x >> 16) & 1u)) >> 16);  // RNE
}
__device__ __forceinline__ bfrag8 pack8(float4 a, float4 b) {
    bfrag8 r;
    r[0] = (short)f2bf(a.x); r[1] = (short)f2bf(a.y);
    r[2] = (short)f2bf(a.z); r[3] = (short)f2bf(a.w);
    r[4] = (short)f2bf(b.x); r[5] = (short)f2bf(b.y);
    r[6] = (short)f2bf(b.z); r[7] = (short)f2bf(b.w);
    return r;
}
__device__ __forceinline__ float sigm(float x) { return 1.0f / (1.0f + __expf(-x)); }
__device__ __forceinline__ float tanh_f(float x) {
    float xc = fminf(fmaxf(x, -15.f), 15.f);
    float e  = __expf(2.f * xc);
    return (e - 1.f) / (e + 1.f);
}
__device__ __forceinline__ float softplus_f(float x) {
    return (x > 15.f) ? x : log1pf(__expf(x));
}

// LLC-coherent write-through dword store (bypasses/doesn't dirty L1+L2).
__device__ __forceinline__ void store_llc_u32(uint32_t* p, uint32_t v) {
    asm volatile("global_store_dword %0, %1, off sc0 sc1"
                 :: "v"(p), "v"(v) : "memory");
}

// Prologue: proj0[j] = dot(W[j, 0:I], bos) + bias[j]  (BOS step, zero state)
__global__ void bos_proj_kernel(const float* __restrict__ W,
                                const float* __restrict__ bos,
                                const float* __restrict__ bias,
                                float* __restrict__ proj0) {
    int j = blockIdx.x * blockDim.x + threadIdx.x;
    if (j >= ND7) return;
    const float* wr = W + (size_t)j * KTOT;
    float s = 0.f;
#pragma unroll 8
    for (int k = 0; k < I_; ++k) s += wr[k] * bos[k];
    proj0[j] = s + bias[j];
}

// Persistent recurrence kernel.
// WG (rg,mg): rows b0..b0+15, state dims m0..m0+15, proj cols {g*512+m0+0..15}.
// Weights pinned in VGPRs (bf16): wave w holds K-steps s = w+4i (i=0..5), 7 N-tiles.
// Sync: per-row-group monotone flag array. Publish = sc1 h-stores -> vmcnt
// drain (__syncthreads) -> relaxed agent flag store. Consume = relaxed agent
// flag poll -> sc1 h-loads. No cache-maintenance instructions anywhere.
__global__ void __launch_bounds__(NTHR, 1)
ctlstm_kernel(const float* __restrict__ X,     // (B,L,I) f32
              const float* __restrict__ DT,    // (B,L)   f32
              const int*   __restrict__ SEQ,   // (B,)    int32
              const float* __restrict__ W,     // (7D, K) f32
              const float* __restrict__ BIAS,  // (7D,)   f32
              const float* __restrict__ PROJ0, // (7D,)   f32
              unsigned short* __restrict__ HBUF, // (2,B,D) bf16 ping-pong (LLC)
              int*   __restrict__ FLAGS,       // RG*MG flags, 64 B apart
              float* __restrict__ OUT)         // f32: outputs (B,L,D) | final (B,4D)
{
    __shared__ float lds[4 * RW * PS];

    const int tid  = threadIdx.x;
    const int wid  = tid >> 6;      // wave 0..3
    const int lane = tid & 63;
    const int bid  = blockIdx.x;
    const int rg   = bid & 7;       // row group (XCD-local under round-robin)
    const int mg   = bid >> 3;      // m group
    const int b0   = rg * RW;
    const int m0   = mg * MW;

    // elementwise mapping: thread <-> (row, mi)
    const int erow = tid >> 4;
    const int emi  = tid & 15;
    const int eb   = b0 + erow;
    const int em   = m0 + emi;
    const int esl  = SEQ[eb];

    // MFMA lane mapping
    const int lrow = lane & 15;     // A row (batch) / B,C col
    const int lq   = lane >> 4;     // quad -> k-octet / C row block
    const int lb   = b0 + lrow;
    const int lsl  = SEQ[lb];

    int* myflag = FLAGS + (rg * MG + mg) * FSTR;
    const int* pollflag = FLAGS + (rg * MG + (lane & 31)) * FSTR;

    uint32_t* HBUF32 = (uint32_t*)HBUF;

    // ---- pin B fragments (weights, f32 -> bf16 RNE): Bf[i][g], K-step s=wid+4i
    bfrag8 Bf[6][7];
#pragma unroll
    for (int i = 0; i < 6; ++i) {
        const int s = wid + 4 * i;
        const int k = s * 32 + lq * 8;
#pragma unroll
        for (int g = 0; g < 7; ++g) {
            const int j = g * D_ + m0 + lrow;       // proj column
            const float4* wp = (const float4*)(W + (size_t)j * KTOT + k);
            Bf[i][g] = pack8(wp[0], wp[1]);
        }
    }

    // bias per elementwise thread (f32)
    float bg[7];
#pragma unroll
    for (int g = 0; g < 7; ++g) bg[g] = BIAS[g * D_ + em];

    // ---- initial state from BOS projection (same for every batch row)
    float p0[7];
#pragma unroll
    for (int g = 0; g < 7; ++g) p0[g] = PROJ0[g * D_ + em];
    float z0  = tanh_f(p0[5]);
    float so  = sigm(p0[4]);          // o
    float scs = sigm(p0[0]) * z0;     // cs = i*z  (c=0)
    float sce = sigm(p0[2]) * z0;     // ce = ie*z (ce=0)
    float sd  = softplus_f(p0[6]);    // d

    const size_t OUTF = (size_t)B_ * L_ * D_;   // final-state offset (f32 elems)

    for (int t = 0; t < L_; ++t) {
        // ---- phase 1: decay + h (uses previous state; local)
        float dtt = (t < esl) ? DT[(size_t)eb * L_ + t] : 0.f;
        float c   = sce + (scs - sce) * __expf(-sd * dtt);
        float h   = so * tanh_f(c);

        // ---- h -> LLC (write-through, pair lanes into dwords; even lanes store)
        unsigned short hb = f2bf(h);
        int partner = __shfl_xor((int)hb, 1, 64);
        if (!(tid & 1)) {
            uint32_t pk = (uint32_t)hb | (((uint32_t)(unsigned short)partner) << 16);
            store_llc_u32(HBUF32 + ((size_t)(t & 1) * B_ + eb) * (D_ / 2) + (em >> 1), pk);
        }

        __syncthreads();   // vmcnt(0): all 4 waves' h-stores acked at LLC

        // ---- publish: relaxed flag store (drain-then-store IS the release)
        if (tid == 0)
            __hip_atomic_store(myflag, t + 1, __ATOMIC_RELAXED,
                               __HIP_MEMORY_SCOPE_AGENT);

        // ---- off-critical-path: f32 output store (cached, lazy writeback)
        OUT[((size_t)eb * L_ + t) * D_ + em] = h;

        // ---- x fragments (s = wid, wid+4), f32 -> bf16; h-independent
        bfrag8 ax[2];
#pragma unroll
        for (int i = 0; i < 2; ++i) {
            const int s = wid + 4 * i;
            const int k = s * 32 + lq * 8;
            float4 xa = {0.f, 0.f, 0.f, 0.f}, xb = {0.f, 0.f, 0.f, 0.f};
            if (t < lsl) {
                const float4* xp = (const float4*)(X + ((size_t)lb * L_ + t) * I_ + k);
                xa = xp[0]; xb = xp[1];
            }
            ax[i] = pack8(xa, xb);
        }

        // ---- x-part MFMAs while the barrier settles
        f32x4 acc[7];
#pragma unroll
        for (int g = 0; g < 7; ++g) acc[g] = (f32x4){0.f, 0.f, 0.f, 0.f};
#pragma unroll
        for (int i = 0; i < 2; ++i)
#pragma unroll
            for (int g = 0; g < 7; ++g)
                acc[g] = __builtin_amdgcn_mfma_f32_16x16x32_bf16(ax[i], Bf[i][g], acc[g], 0, 0, 0);

        // ---- wait: wave 0 polls all 32 flags lane-parallel (relaxed agent)
        if (wid == 0) {
            while (true) {
                int v = __hip_atomic_load(pollflag, __ATOMIC_RELAXED,
                                          __HIP_MEMORY_SCOPE_AGENT);
                if (__all(v >= t + 1)) break;
                __builtin_amdgcn_s_sleep(2);
            }
        }
        __syncthreads();

        // ---- h fragments straight from LLC (sc0 sc1: bypass L1/L2, no stale copies)
        const unsigned short* hrow = HBUF + (size_t)((t & 1) * B_ + lb) * D_;
        const int kb = wid * 32 + lq * 8;           // s=wid+8 base -> k = wid*32+lq*8
        bfrag8 ah0, ah1, ah2, ah3;
        asm volatile(
            "global_load_dwordx4 %0, %4, off sc0 sc1\n\t"
            "global_load_dwordx4 %1, %5, off sc0 sc1\n\t"
            "global_load_dwordx4 %2, %6, off sc0 sc1\n\t"
            "global_load_dwordx4 %3, %7, off sc0 sc1\n\t"
            "s_waitcnt vmcnt(0)"
            : "=&v"(ah0), "=&v"(ah1), "=&v"(ah2), "=&v"(ah3)
            : "v"(hrow + kb), "v"(hrow + kb + 128),
              "v"(hrow + kb + 256), "v"(hrow + kb + 384)
            : "memory");

        // ---- h-part MFMAs (K-steps s = 8..23)
#pragma unroll
        for (int g = 0; g < 7; ++g) {
            acc[g] = __builtin_amdgcn_mfma_f32_16x16x32_bf16(ah0, Bf[2][g], acc[g], 0, 0, 0);
            acc[g] = __builtin_amdgcn_mfma_f32_16x16x32_bf16(ah1, Bf[3][g], acc[g], 0, 0, 0);
            acc[g] = __builtin_amdgcn_mfma_f32_16x16x32_bf16(ah2, Bf[4][g], acc[g], 0, 0, 0);
            acc[g] = __builtin_amdgcn_mfma_f32_16x16x32_bf16(ah3, Bf[5][g], acc[g], 0, 0, 0);
        }

        // ---- cross-wave K-reduction via LDS
        // C/D layout: col = lane&15, row = (lane>>4)*4 + reg  (m89/m91)
#pragma unroll
        for (int g = 0; g < 7; ++g)
#pragma unroll
            for (int r = 0; r < 4; ++r)
                lds[(wid * RW + lq * 4 + r) * PS + g * 16 + lrow] = acc[g][r];

        __syncthreads();

        // ---- phase 4: gates + state update (local)
        float p[7];
#pragma unroll
        for (int g = 0; g < 7; ++g) {
            float s = bg[g];
#pragma unroll
            for (int w2 = 0; w2 < 4; ++w2)
                s += lds[(w2 * RW + erow) * PS + g * 16 + emi];
            p[g] = s;
        }
        float ig  = sigm(p[0]);
        float fg  = sigm(p[1]);
        float ieg = sigm(p[2]);
        float feg = sigm(p[3]);
        float on  = sigm(p[4]);
        float z   = tanh_f(p[5]);
        float dn  = softplus_f(p[6]);
        float csn = fg * c + ig * z;
        float cen = feg * sce + ieg * z;
        so = on; scs = csn; sce = cen; sd = dn;

        if (t == esl - 1) {   // capture final state (post-update) at seq_len-1
            size_t fo = OUTF + (size_t)eb * (4 * D_) + em;
            OUT[fo]          = on;
            OUT[fo + D_]     = csn;
            OUT[fo + 2 * D_] = cen;
            OUT[fo + 3 * D_] = dn;
        }
        // LDS WAR across steps: guarded by post-spin __syncthreads of next step
    }
}

extern "C" void kernel_launch(void* const* d_in, const int* in_sizes, int n_in,
                              void* d_out, int out_size, void* d_ws, size_t ws_size,
                              hipStream_t stream) {
    const float* X   = (const float*)d_in[0];
    const float* DT  = (const float*)d_in[1];
    const int*   SEQ = (const int*)d_in[2];
    const float* BOS = (const float*)d_in[3];
    const float* W   = (const float*)d_in[4];
    const float* BI  = (const float*)d_in[5];
    float*       OUT = (float*)d_out;

    float*          proj0 = (float*)d_ws;                              // 14336 B
    int*            flags = (int*)((char*)d_ws + 16384);               // 256 x 64 B
    unsigned short* hbuf  = (unsigned short*)((char*)d_ws + 49152);    // 2*B*D bf16 = 256 KB

    // flags must start at zero (d_ws is poisoned 0xAA each call)
    hipMemsetAsync((char*)d_ws + 16384, 0, 16384, stream);

    bos_proj_kernel<<<(ND7 + 255) / 256, 256, 0, stream>>>(W, BOS, BI, proj0);

    ctlstm_kernel<<<dim3(NWG), dim3(NTHR), 0, stream>>>(
        X, DT, SEQ, W, BI, proj0, hbuf, flags, OUT);
}